// Round 2
// baseline (1126.604 us; speedup 1.0000x reference)
//
#include <hip/hip_runtime.h>
#include <hip/hip_bf16.h>
#include <math.h>

#define HID 64
#define HEADS 4
#define LAYERS 4
#define NRBF 20
#define NG 256
#define CB 512     // HID*8 floats per node (channels x blades)
#define CAPE 512   // max edges per LDS chunk in aggregation
#define PROJ_NODES 32  // nodes per proj block (8 waves x 4 nodes)

__device__ __forceinline__ int gradeOf(int b){ return (b==0)?0:((b<4)?1:((b<7)?2:3)); }

// ---------- prep: weights into coalescing-friendly layouts ----------
// WT4[((l*4096)+(i*64+o))*4+g] = proj_w[l][g][o][i]   (float4 per (i,o) = 4 grades)
__global__ void prep_kernel(const float* __restrict__ proj_w, const float* __restrict__ inproj_w,
                            const float* __restrict__ prepool_w, const float* __restrict__ post_w1,
                            float* __restrict__ WT4, float* __restrict__ inwT,
                            float* __restrict__ ppw0T, float* __restrict__ w1T){
    int idx = blockIdx.x*256 + threadIdx.x;
    const int szW = LAYERS*64*64*4;          // 65536
    if (idx < szW){
        int g = idx & 3; int o = (idx>>2)&63; int i = (idx>>8)&63; int l = idx>>14;
        WT4[idx] = proj_w[(((size_t)l*4+g)*HID + o)*HID + i];
    } else if (idx < szW + 65*HID){
        int r = idx - szW; int i = r/HID, o = r%HID;
        inwT[r] = inproj_w[o*65 + i];
    } else if (idx < szW + 65*HID + HID*HID){
        int r = idx - szW - 65*HID; int i = r/HID, o = r%HID;
        ppw0T[r] = prepool_w[o*HID + i];
    } else if (idx < szW + 65*HID + 2*HID*HID){
        int r = idx - szW - 65*HID - HID*HID; int i = r/HID, o = r%HID;
        w1T[r] = post_w1[o*HID + i];
    }
}

// ---------- per-graph position sums for centering ----------
__global__ void node_stats_kernel(const float* __restrict__ pos, const int* __restrict__ batch,
                                  float* possum, float* pcnt, int N){
    int n = blockIdx.x*256 + threadIdx.x; if (n>=N) return;
    int g = batch[n];
    atomicAdd(&possum[g*3+0], pos[n*3+0]);
    atomicAdd(&possum[g*3+1], pos[n*3+1]);
    atomicAdd(&possum[g*3+2], pos[n*3+2]);
    atomicAdd(&pcnt[g], 1.0f);
}

// ---------- edge MLP: dist -> RBF(20) -> 64 (silu) -> 4, plus dst-degree count ----------
__global__ void edge_kernel(const float* __restrict__ pos, const int* __restrict__ ei, int E,
                            const float* __restrict__ ew1, const float* __restrict__ eb1,
                            const float* __restrict__ ew2, const float* __restrict__ eb2,
                            float* __restrict__ edge_scalar, int* counts){
    __shared__ float w1[HID*NRBF], b1[HID], w2[HEADS*HID], b2s[HEADS];
    for (int i=threadIdx.x;i<HID*NRBF;i+=blockDim.x) w1[i]=ew1[i];
    for (int i=threadIdx.x;i<HID;i+=blockDim.x) b1[i]=eb1[i];
    for (int i=threadIdx.x;i<HEADS*HID;i+=blockDim.x) w2[i]=ew2[i];
    if (threadIdx.x<HEADS) b2s[threadIdx.x]=eb2[threadIdx.x];
    __syncthreads();
    int e = blockIdx.x*blockDim.x + threadIdx.x; if (e>=E) return;
    int s = ei[e], d = ei[E+e];
    float dx = pos[s*3+0]-pos[d*3+0];
    float dy = pos[s*3+1]-pos[d*3+1];
    float dz = pos[s*3+2]-pos[d*3+2];
    float dist = sqrtf(dx*dx+dy*dy+dz*dz);
    float t0 = dist * (19.0f/10.0f);
    float rbf[NRBF];
    #pragma unroll
    for (int k=0;k<NRBF;k++){ float a = t0 - (float)k; rbf[k]=__expf(-0.5f*a*a); }
    float acc0=b2s[0], acc1=b2s[1], acc2=b2s[2], acc3=b2s[3];
    for (int o=0;o<HID;o++){
        float hv = b1[o];
        #pragma unroll
        for (int k=0;k<NRBF;k++) hv += rbf[k]*w1[o*NRBF+k];
        float act = hv * (1.0f/(1.0f+__expf(-hv)));
        acc0 += act*w2[0*HID+o]; acc1 += act*w2[1*HID+o];
        acc2 += act*w2[2*HID+o]; acc3 += act*w2[3*HID+o];
    }
    float4* ep = (float4*)&edge_scalar[e*4];
    ep[0] = make_float4(acc0,acc1,acc2,acc3);
    atomicAdd(&counts[d],1);
}

// ---------- single-block shuffle scan of dst counts -> CSR indptr + cursor; also pos means ----------
__global__ void scan_kernel(const int* __restrict__ counts, int* indptr, int* cursor, int N,
                            const float* __restrict__ possum, const float* __restrict__ pcnt,
                            float* pmean){
    __shared__ int wsum[16];
    __shared__ int carry_s;
    int t = threadIdx.x; int lane = t&63, w = t>>6;
    if (t==0) carry_s = 0;
    __syncthreads();
    for (int base=0; base<N; base+=1024){
        int v = (base+t<N)? counts[base+t] : 0;
        int x = v;
        #pragma unroll
        for (int off=1; off<64; off<<=1){ int y=__shfl_up(x,off,64); if (lane>=off) x+=y; }
        if (lane==63) wsum[w]=x;
        __syncthreads();
        if (w==0 && lane<16){
            int s = wsum[lane];
            #pragma unroll
            for (int off=1; off<16; off<<=1){ int y=__shfl_up(s,off,64); if (lane>=off) s+=y; }
            wsum[lane]=s;
        }
        __syncthreads();
        int excl = carry_s + (w>0? wsum[w-1]:0) + x - v;
        if (base+t<N){ indptr[base+t]=excl; cursor[base+t]=excl; }
        __syncthreads();
        if (t==1023) carry_s = carry_s + wsum[15];
        __syncthreads();
    }
    if (t==0) indptr[N]=carry_s;
    for (int i=t;i<NG;i+=1024){
        float c = pcnt[i]; float cm = c>1.0f?c:1.0f;
        pmean[i*3+0]=possum[i*3+0]/cm;
        pmean[i*3+1]=possum[i*3+1]/cm;
        pmean[i*3+2]=possum[i*3+2]/cm;
    }
}

__global__ void fill_kernel(const int* __restrict__ ei, int E, int* cursor, int* eids){
    int e = blockIdx.x*blockDim.x + threadIdx.x; if (e>=E) return;
    int d = ei[E+e];
    int p = atomicAdd(&cursor[d],1);
    eids[p]=e;
}

// ---------- initial node embedding ----------
__global__ void embed_kernel(const float* __restrict__ atom_w, const int* __restrict__ zidx,
                             const float* __restrict__ inwT, const float* __restrict__ inb,
                             const float* __restrict__ pos, const float* __restrict__ pmean,
                             const int* __restrict__ batch, float* __restrict__ h, int N){
    int n = blockIdx.x; int o = threadIdx.x;     // 64 threads
    __shared__ float emb[HID];
    emb[o] = atom_w[zidx[n]*HID + o];
    __syncthreads();
    float acc = inb[o];
    for (int i=0;i<HID;i++) acc += emb[i]*inwT[i*HID+o];
    int g = batch[n];
    float px = pos[n*3+0]-pmean[g*3+0];
    float py = pos[n*3+1]-pmean[g*3+1];
    float pz = pos[n*3+2]-pmean[g*3+2];
    float wv = inwT[HID*HID + o];                // inproj_w[o][64]
    float4* hp = (float4*)&h[(size_t)n*CB + o*8];
    hp[0] = make_float4(acc, wv*px, wv*py, wv*pz);
    hp[1] = make_float4(0.f,0.f,0.f,0.f);
}

// ---------- MVLinear projection + fused s-logits + bf16 z output ----------
// block: 512 threads = 8 waves; wave w handles 4 nodes; lane = output channel o.
// weights staged in LDS as float4 (4 grades) per (i,o); h read via wave-uniform global float4.
__global__ __launch_bounds__(512) void proj_kernel(const float* __restrict__ h, const float* __restrict__ WT4l,
                            const float* __restrict__ pbl,
                            const float* __restrict__ a_src_l, const float* __restrict__ a_dst_l,
                            const float* __restrict__ w_src_l, const float* __restrict__ w_dst_l,
                            __hip_bfloat16* __restrict__ z16, float* __restrict__ s_src,
                            float* __restrict__ s_dst, int N){
    __shared__ float4 wlds[64*64];               // 64 KB
    int t = threadIdx.x;
    const float4* wg = (const float4*)WT4l;
    #pragma unroll
    for (int k=0;k<8;k++) wlds[t + k*512] = wg[t + k*512];
    __syncthreads();
    int w = t>>6, o = t&63;
    int head = o>>4;
    int n0 = blockIdx.x*PROJ_NODES + w*4;
    const float* h0 = h + (size_t)n0*CB;
    float acc[4][8];
    #pragma unroll
    for (int m=0;m<4;m++)
        #pragma unroll
        for (int k=0;k<8;k++) acc[m][k]=0.f;
    #pragma unroll 4
    for (int i=0;i<64;i++){
        float4 wv = wlds[i*64+o];                // ds_read_b128, lanes consecutive
        #pragma unroll
        for (int m=0;m<4;m++){
            const float* hr = h0 + (size_t)m*CB + i*8;
            float4 ha = *(const float4*)hr;       // wave-uniform → L1 broadcast
            float4 hb = *(const float4*)(hr+4);
            acc[m][0] += wv.x*ha.x;
            acc[m][1] += wv.y*ha.y;
            acc[m][2] += wv.y*ha.z;
            acc[m][3] += wv.y*ha.w;
            acc[m][4] += wv.z*hb.x;
            acc[m][5] += wv.z*hb.y;
            acc[m][6] += wv.z*hb.z;
            acc[m][7] += wv.w*hb.w;
        }
    }
    float bias = pbl[o];
    // fold attention contraction vectors once
    float as8[8], ad8[8];
    #pragma unroll
    for (int k=0;k<8;k++){
        int g = gradeOf(k);
        as8[k] = a_src_l[o*8+k]*w_src_l[head*4+g];
        ad8[k] = a_dst_l[o*8+k]*w_dst_l[head*4+g];
    }
    #pragma unroll
    for (int m=0;m<4;m++){
        int n = n0+m; if (n>=N) break;
        acc[m][0] += bias;
        float ps=0.f, pd=0.f;
        #pragma unroll
        for (int k=0;k<8;k++){ ps += acc[m][k]*as8[k]; pd += acc[m][k]*ad8[k]; }
        #pragma unroll
        for (int off=1; off<16; off<<=1){ ps += __shfl_xor(ps,off,64); pd += __shfl_xor(pd,off,64); }
        if ((o&15)==0){ s_src[n*4+head]=ps; s_dst[n*4+head]=pd; }
        __hip_bfloat16 tmp[8];
        #pragma unroll
        for (int k=0;k<8;k++) tmp[k]=__float2bfloat16(acc[m][k]);
        *(int4*)(z16 + (size_t)n*CB + o*8) = *(int4*)tmp;
    }
}

// ---------- fused: softmax attention aggregate (bf16 gather) + mvSiLU + residual + mvLayerNorm ----------
__global__ __launch_bounds__(512) void agg_kernel(const __hip_bfloat16* __restrict__ z16,
                           const float* __restrict__ s_src, const float* __restrict__ s_dst,
                           const float* __restrict__ esc,
                           const int* __restrict__ eids, const int* __restrict__ indptr,
                           const int* __restrict__ ei, int E,
                           const float* __restrict__ silu_a_l, const float* __restrict__ silu_b_l,
                           const float* __restrict__ ln_a_l, float* __restrict__ h, int N){
    int n = blockIdx.x; int t = threadIdx.x;
    int wv = t>>6, lane = t&63;
    int b = t&7, c = t>>3;
    __shared__ float sdl[4];
    __shared__ float mred[8][4];
    __shared__ float mfin[4];
    __shared__ int   le[CAPE];
    __shared__ float lwT[4*CAPE];
    __shared__ float accf[8][520];
    __shared__ float dnp[8][4];
    __shared__ float xs[CB];
    __shared__ float ncs[HID];
    __shared__ float mean_s;
    int beg = indptr[n], end = indptr[n+1];
    int deg = end-beg;
    bool fast = deg <= CAPE;
    if (t<4) sdl[t] = s_dst[n*4+t];
    __syncthreads();
    // pass A: per-head max of leaky_relu logits (cache pre-exp logits if they fit)
    float m0=-1e30f,m1=-1e30f,m2=-1e30f,m3=-1e30f;
    for (int idx=beg+t; idx<end; idx+=512){
        int e = eids[idx]; int s = ei[e];
        float4 sv = *(const float4*)&s_src[s*4];
        float4 ev = *(const float4*)&esc[e*4];
        float e0 = sv.x+sdl[0]+ev.x; e0=(e0>=0.f)?e0:0.2f*e0;
        float e1 = sv.y+sdl[1]+ev.y; e1=(e1>=0.f)?e1:0.2f*e1;
        float e2 = sv.z+sdl[2]+ev.z; e2=(e2>=0.f)?e2:0.2f*e2;
        float e3 = sv.w+sdl[3]+ev.w; e3=(e3>=0.f)?e3:0.2f*e3;
        if (fast){
            int tt = idx-beg;
            le[tt]=s;
            lwT[0*CAPE+tt]=e0; lwT[1*CAPE+tt]=e1; lwT[2*CAPE+tt]=e2; lwT[3*CAPE+tt]=e3;
        }
        m0=fmaxf(m0,e0); m1=fmaxf(m1,e1); m2=fmaxf(m2,e2); m3=fmaxf(m3,e3);
    }
    #pragma unroll
    for (int off=1; off<64; off<<=1){
        m0=fmaxf(m0,__shfl_xor(m0,off,64)); m1=fmaxf(m1,__shfl_xor(m1,off,64));
        m2=fmaxf(m2,__shfl_xor(m2,off,64)); m3=fmaxf(m3,__shfl_xor(m3,off,64));
    }
    if (lane==0){ mred[wv][0]=m0; mred[wv][1]=m1; mred[wv][2]=m2; mred[wv][3]=m3; }
    __syncthreads();
    if (t<4){
        float mm=-1e30f;
        for (int w=0;w<8;w++) mm=fmaxf(mm,mred[w][t]);
        mfin[t]=mm;
    }
    __syncthreads();
    // pass B: wave-per-edge bf16 gather, fused numerator + denominator
    float acc[8];
    #pragma unroll
    for (int k=0;k<8;k++) acc[k]=0.f;
    float dnl = 0.f;
    int headl = lane>>4;
    for (int base=beg; base<end; base+=CAPE){
        int cnt = min(CAPE, end-base);
        if (!fast && t<cnt){
            int e = eids[base+t]; int s = ei[e];
            float4 sv = *(const float4*)&s_src[s*4];
            float4 ev = *(const float4*)&esc[e*4];
            float e0 = sv.x+sdl[0]+ev.x; e0=(e0>=0.f)?e0:0.2f*e0;
            float e1 = sv.y+sdl[1]+ev.y; e1=(e1>=0.f)?e1:0.2f*e1;
            float e2 = sv.z+sdl[2]+ev.z; e2=(e2>=0.f)?e2:0.2f*e2;
            float e3 = sv.w+sdl[3]+ev.w; e3=(e3>=0.f)?e3:0.2f*e3;
            le[t]=s;
            lwT[0*CAPE+t]=e0; lwT[1*CAPE+t]=e1; lwT[2*CAPE+t]=e2; lwT[3*CAPE+t]=e3;
        }
        __syncthreads();
        if (t<cnt){
            lwT[0*CAPE+t]=__expf(lwT[0*CAPE+t]-mfin[0]);
            lwT[1*CAPE+t]=__expf(lwT[1*CAPE+t]-mfin[1]);
            lwT[2*CAPE+t]=__expf(lwT[2*CAPE+t]-mfin[2]);
            lwT[3*CAPE+t]=__expf(lwT[3*CAPE+t]-mfin[3]);
        }
        __syncthreads();
        for (int j=wv; j<cnt; j+=8){
            float wj = lwT[headl*CAPE+j];
            const int4* zp = (const int4*)(z16 + (size_t)le[j]*CB) + lane;
            int4 zv = *zp;                        // 16B = 8 bf16; wave covers full 1KB row
            unsigned u0=(unsigned)zv.x, u1=(unsigned)zv.y, u2=(unsigned)zv.z, u3=(unsigned)zv.w;
            acc[0] += wj*__uint_as_float(u0<<16);
            acc[1] += wj*__uint_as_float(u0&0xFFFF0000u);
            acc[2] += wj*__uint_as_float(u1<<16);
            acc[3] += wj*__uint_as_float(u1&0xFFFF0000u);
            acc[4] += wj*__uint_as_float(u2<<16);
            acc[5] += wj*__uint_as_float(u2&0xFFFF0000u);
            acc[6] += wj*__uint_as_float(u3<<16);
            acc[7] += wj*__uint_as_float(u3&0xFFFF0000u);
            dnl += wj;
        }
        __syncthreads();
    }
    // cross-wave reduction
    #pragma unroll
    for (int k=0;k<8;k++) accf[wv][lane*8+k]=acc[k];
    if ((lane&15)==0) dnp[wv][headl]=dnl;
    __syncthreads();
    float x=0.f;
    #pragma unroll
    for (int w=0;w<8;w++) x += accf[w][t];
    int head = t>>7;
    float dn=0.f;
    #pragma unroll
    for (int w=0;w<8;w++) dn += dnp[w][head];
    x /= (dn + 1e-16f);
    xs[t]=x; __syncthreads();
    // mvSiLU
    int g = gradeOf(b);
    int cb = c*8;
    float norm;
    if (g==0)      norm = xs[cb];
    else if (g==1) norm = xs[cb+1]*xs[cb+1]+xs[cb+2]*xs[cb+2]+xs[cb+3]*xs[cb+3];
    else if (g==2) norm = xs[cb+4]*xs[cb+4]+xs[cb+5]*xs[cb+5]+xs[cb+6]*xs[cb+6];
    else           norm = xs[cb+7]*xs[cb+7];
    float gate = 1.0f/(1.0f+__expf(-(silu_a_l[c*4+g]*norm + silu_b_l[c*4+g])));
    float val = gate*x + h[(size_t)n*CB + t];     // + residual
    __syncthreads();
    xs[t]=val; __syncthreads();
    // mvLayerNorm
    if (b==0){
        float ss=0.f;
        #pragma unroll
        for (int k=0;k<8;k++){ float v=xs[cb+k]; ss+=v*v; }
        ncs[c]=sqrtf(ss);
    }
    __syncthreads();
    if (wv==0){
        float v = ncs[lane];
        #pragma unroll
        for (int off=1; off<64; off<<=1) v += __shfl_xor(v,off,64);
        if (lane==0) mean_s = v*(1.0f/64.0f) + 1e-6f;
    }
    __syncthreads();
    h[(size_t)n*CB + t] = ln_a_l[c]*val/mean_s;
}

// ---------- prepool (scalar blade) + graph readout sum ----------
__global__ void prepool_kernel(const float* __restrict__ h, const float* __restrict__ ppw0T,
                               const float* __restrict__ ppb, const int* __restrict__ batch,
                               float* g, int N){
    int n = blockIdx.x; int o = threadIdx.x;  // 64 threads
    __shared__ float xs[HID];
    xs[o] = h[(size_t)n*CB + o*8];
    __syncthreads();
    float acc = ppb[o];
    for (int i=0;i<HID;i++) acc += xs[i]*ppw0T[i*HID+o];
    atomicAdd(&g[batch[n]*HID + o], acc);
}

__global__ void final_kernel(const float* __restrict__ g, const float* __restrict__ w1T,
                             const float* __restrict__ b1, const float* __restrict__ w2,
                             const float* __restrict__ b2, float* out){
    int gid = blockIdx.x; int o = threadIdx.x;  // 64 threads = 1 wave
    __shared__ float gl[HID];
    gl[o] = g[gid*HID + o]; __syncthreads();
    float a = b1[o];
    for (int i=0;i<HID;i++) a += gl[i]*w1T[i*HID+o];
    float act = a/(1.0f+__expf(-a));
    float p = act * w2[o];
    #pragma unroll
    for (int off=1; off<64; off<<=1) p += __shfl_xor(p,off,64);
    if (o==0) out[gid] = p + b2[0];
}

extern "C" void kernel_launch(void* const* d_in, const int* in_sizes, int n_in,
                              void* d_out, int out_size, void* d_ws, size_t ws_size,
                              hipStream_t stream) {
    const float* pos      = (const float*)d_in[0];
    const int*   zidx     = (const int*)  d_in[1];
    const int*   ei       = (const int*)  d_in[2];
    const int*   batch    = (const int*)  d_in[3];
    const float* atom_w   = (const float*)d_in[4];
    const float* inproj_w = (const float*)d_in[5];
    const float* inproj_b = (const float*)d_in[6];
    const float* edge_w1  = (const float*)d_in[7];
    const float* edge_b1  = (const float*)d_in[8];
    const float* edge_w2  = (const float*)d_in[9];
    const float* edge_b2  = (const float*)d_in[10];
    const float* proj_w   = (const float*)d_in[11];
    const float* proj_b   = (const float*)d_in[12];
    const float* a_src    = (const float*)d_in[13];
    const float* a_dst    = (const float*)d_in[14];
    const float* w_src    = (const float*)d_in[15];
    const float* w_dst    = (const float*)d_in[16];
    const float* ln_a     = (const float*)d_in[17];
    const float* silu_a   = (const float*)d_in[18];
    const float* silu_b   = (const float*)d_in[19];
    const float* prepool_w= (const float*)d_in[20];
    const float* prepool_b= (const float*)d_in[21];
    const float* post_w1  = (const float*)d_in[22];
    const float* post_b1  = (const float*)d_in[23];
    const float* post_w2  = (const float*)d_in[24];
    const float* post_b2  = (const float*)d_in[25];
    float* out = (float*)d_out;

    const int N = in_sizes[0]/3;
    const int E = in_sizes[2]/2;

    float* wsf = (float*)d_ws;
    size_t off = 0;
    auto alloc = [&](size_t nelem){ size_t r = off; off += (nelem + 63) & ~(size_t)63; return r; };
    size_t o_counts = alloc(N);          // int
    size_t o_possum = alloc(NG*3);
    size_t o_pcnt   = alloc(NG);
    size_t o_g      = alloc(NG*HID);
    size_t zero_end = off;
    size_t o_indptr = alloc(N+1);        // int
    size_t o_cursor = alloc(N);          // int
    size_t o_eids   = alloc(E);          // int
    size_t o_pmean  = alloc(NG*3);
    size_t o_esc    = alloc((size_t)E*4);
    size_t o_ssrc   = alloc((size_t)N*4);
    size_t o_sdst   = alloc((size_t)N*4);
    size_t o_inwT   = alloc(65*HID);
    size_t o_WT4    = alloc((size_t)LAYERS*64*64*4);
    size_t o_ppw0T  = alloc(HID*HID);
    size_t o_w1T    = alloc(HID*HID);
    size_t o_h      = alloc((size_t)N*CB);
    size_t o_z16    = alloc((size_t)N*CB/2);   // bf16: N*512 halves = N*256 floats

    int*   counts = (int*)(wsf + o_counts);
    float* possum = wsf + o_possum;
    float* pcnt   = wsf + o_pcnt;
    float* gbuf   = wsf + o_g;
    int*   indptr = (int*)(wsf + o_indptr);
    int*   cursor = (int*)(wsf + o_cursor);
    int*   eids   = (int*)(wsf + o_eids);
    float* pmean  = wsf + o_pmean;
    float* esc    = wsf + o_esc;
    float* ssrc   = wsf + o_ssrc;
    float* sdst   = wsf + o_sdst;
    float* inwT   = wsf + o_inwT;
    float* WT4    = wsf + o_WT4;
    float* ppw0T  = wsf + o_ppw0T;
    float* w1T    = wsf + o_w1T;
    float* hbuf   = wsf + o_h;
    __hip_bfloat16* z16 = (__hip_bfloat16*)(wsf + o_z16);

    hipMemsetAsync(wsf, 0, zero_end*sizeof(float), stream);

    {
        int total = LAYERS*64*64*4 + 65*HID + 2*HID*HID;
        prep_kernel<<<(total+255)/256, 256, 0, stream>>>(proj_w, inproj_w, prepool_w, post_w1,
                                                         WT4, inwT, ppw0T, w1T);
    }
    node_stats_kernel<<<(N+255)/256, 256, 0, stream>>>(pos, batch, possum, pcnt, N);
    edge_kernel<<<(E+255)/256, 256, 0, stream>>>(pos, ei, E, edge_w1, edge_b1, edge_w2, edge_b2,
                                                 esc, counts);
    scan_kernel<<<1, 1024, 0, stream>>>(counts, indptr, cursor, N, possum, pcnt, pmean);
    fill_kernel<<<(E+255)/256, 256, 0, stream>>>(ei, E, cursor, eids);
    embed_kernel<<<N, HID, 0, stream>>>(atom_w, zidx, inwT, inproj_b, pos, pmean, batch, hbuf, N);

    for (int l=0; l<LAYERS; l++){
        proj_kernel<<<(N+PROJ_NODES-1)/PROJ_NODES, 512, 0, stream>>>(
            hbuf, WT4 + (size_t)l*64*64*4, proj_b + l*HID,
            a_src + l*512, a_dst + l*512, w_src + l*16, w_dst + l*16,
            z16, ssrc, sdst, N);
        agg_kernel<<<N, 512, 0, stream>>>(z16, ssrc, sdst, esc, eids, indptr, ei, E,
                                          silu_a + l*HID*4, silu_b + l*HID*4,
                                          ln_a + l*HID, hbuf, N);
    }

    prepool_kernel<<<N, HID, 0, stream>>>(hbuf, ppw0T, prepool_b, batch, gbuf, N);
    final_kernel<<<NG, HID, 0, stream>>>(gbuf, w1T, post_b1, post_w2, post_b2, out);
}

// Round 3
// 679.508 us; speedup vs baseline: 1.6580x; 1.6580x over previous
//
#include <hip/hip_runtime.h>
#include <hip/hip_bf16.h>
#include <math.h>

#define HID 64
#define HEADS 4
#define LAYERS 4
#define NRBF 20
#define NG 256
#define CB 512     // HID*8 floats per node (channels x blades)

typedef __attribute__((ext_vector_type(8))) short short8;
typedef __attribute__((ext_vector_type(4))) float floatx4;

__device__ __forceinline__ int gradeOf(int b){ return (b==0)?0:((b<4)?1:((b<7)?2:3)); }
__device__ __forceinline__ unsigned short f2bf(float f){
    __hip_bfloat16 h = __float2bfloat16(f);
    return *(unsigned short*)&h;
}
__device__ __forceinline__ float bflo(int u){ return __uint_as_float(((unsigned)u)<<16); }
__device__ __forceinline__ float bfhi(int u){ return __uint_as_float(((unsigned)u)&0xFFFF0000u); }

// ---------- prep: WTbf[l][g][o][i] = bf16(proj_w) (same order, cast); plus f32 transposes ----------
__global__ void prep_kernel(const float* __restrict__ proj_w, const float* __restrict__ inproj_w,
                            const float* __restrict__ prepool_w, const float* __restrict__ post_w1,
                            unsigned short* __restrict__ WTbf, float* __restrict__ inwT,
                            float* __restrict__ ppw0T, float* __restrict__ w1T){
    int idx = blockIdx.x*256 + threadIdx.x;
    const int szW = LAYERS*4*64*64;          // 65536
    if (idx < szW){
        WTbf[idx] = f2bf(proj_w[idx]);
    } else if (idx < szW + 65*HID){
        int r = idx - szW; int i = r/HID, o = r%HID;
        inwT[r] = inproj_w[o*65 + i];
    } else if (idx < szW + 65*HID + HID*HID){
        int r = idx - szW - 65*HID; int i = r/HID, o = r%HID;
        ppw0T[r] = prepool_w[o*HID + i];
    } else if (idx < szW + 65*HID + 2*HID*HID){
        int r = idx - szW - 65*HID - HID*HID; int i = r/HID, o = r%HID;
        w1T[r] = post_w1[o*HID + i];
    }
}

// ---------- per-graph position sums for centering ----------
__global__ void node_stats_kernel(const float* __restrict__ pos, const int* __restrict__ batch,
                                  float* possum, float* pcnt, int N){
    int n = blockIdx.x*256 + threadIdx.x; if (n>=N) return;
    int g = batch[n];
    atomicAdd(&possum[g*3+0], pos[n*3+0]);
    atomicAdd(&possum[g*3+1], pos[n*3+1]);
    atomicAdd(&possum[g*3+2], pos[n*3+2]);
    atomicAdd(&pcnt[g], 1.0f);
}

// ---------- edge MLP: dist -> RBF(20) -> 64 (silu) -> 4, plus dst-degree count ----------
__global__ void edge_kernel(const float* __restrict__ pos, const int* __restrict__ ei, int E,
                            const float* __restrict__ ew1, const float* __restrict__ eb1,
                            const float* __restrict__ ew2, const float* __restrict__ eb2,
                            float* __restrict__ edge_scalar, int* counts){
    __shared__ float w1[HID*NRBF], b1[HID], w2[HEADS*HID], b2s[HEADS];
    for (int i=threadIdx.x;i<HID*NRBF;i+=blockDim.x) w1[i]=ew1[i];
    for (int i=threadIdx.x;i<HID;i+=blockDim.x) b1[i]=eb1[i];
    for (int i=threadIdx.x;i<HEADS*HID;i+=blockDim.x) w2[i]=ew2[i];
    if (threadIdx.x<HEADS) b2s[threadIdx.x]=eb2[threadIdx.x];
    __syncthreads();
    int e = blockIdx.x*blockDim.x + threadIdx.x; if (e>=E) return;
    int s = ei[e], d = ei[E+e];
    float dx = pos[s*3+0]-pos[d*3+0];
    float dy = pos[s*3+1]-pos[d*3+1];
    float dz = pos[s*3+2]-pos[d*3+2];
    float dist = sqrtf(dx*dx+dy*dy+dz*dz);
    float t0 = dist * (19.0f/10.0f);
    float rbf[NRBF];
    #pragma unroll
    for (int k=0;k<NRBF;k++){ float a = t0 - (float)k; rbf[k]=__expf(-0.5f*a*a); }
    float acc0=b2s[0], acc1=b2s[1], acc2=b2s[2], acc3=b2s[3];
    for (int o=0;o<HID;o++){
        float hv = b1[o];
        #pragma unroll
        for (int k=0;k<NRBF;k++) hv += rbf[k]*w1[o*NRBF+k];
        float act = hv * (1.0f/(1.0f+__expf(-hv)));
        acc0 += act*w2[0*HID+o]; acc1 += act*w2[1*HID+o];
        acc2 += act*w2[2*HID+o]; acc3 += act*w2[3*HID+o];
    }
    float4* ep = (float4*)&edge_scalar[e*4];
    ep[0] = make_float4(acc0,acc1,acc2,acc3);
    atomicAdd(&counts[d],1);
}

// ---------- single-block shuffle scan -> CSR indptr + cursor; pos means ----------
__global__ void scan_kernel(const int* __restrict__ counts, int* indptr, int* cursor, int N,
                            const float* __restrict__ possum, const float* __restrict__ pcnt,
                            float* pmean){
    __shared__ int wsum[16];
    __shared__ int carry_s;
    int t = threadIdx.x; int lane = t&63, w = t>>6;
    if (t==0) carry_s = 0;
    __syncthreads();
    for (int base=0; base<N; base+=1024){
        int v = (base+t<N)? counts[base+t] : 0;
        int x = v;
        #pragma unroll
        for (int off=1; off<64; off<<=1){ int y=__shfl_up(x,off,64); if (lane>=off) x+=y; }
        if (lane==63) wsum[w]=x;
        __syncthreads();
        if (w==0 && lane<16){
            int s = wsum[lane];
            #pragma unroll
            for (int off=1; off<16; off<<=1){ int y=__shfl_up(s,off,64); if (lane>=off) s+=y; }
            wsum[lane]=s;
        }
        __syncthreads();
        int excl = carry_s + (w>0? wsum[w-1]:0) + x - v;
        if (base+t<N){ indptr[base+t]=excl; cursor[base+t]=excl; }
        __syncthreads();
        if (t==1023) carry_s = carry_s + wsum[15];
        __syncthreads();
    }
    if (t==0) indptr[N]=carry_s;
    for (int i=t;i<NG;i+=1024){
        float c = pcnt[i]; float cm = c>1.0f?c:1.0f;
        pmean[i*3+0]=possum[i*3+0]/cm;
        pmean[i*3+1]=possum[i*3+1]/cm;
        pmean[i*3+2]=possum[i*3+2]/cm;
    }
}

__global__ void fill_kernel(const int* __restrict__ ei, int E, int* cursor, int* eids){
    int e = blockIdx.x*blockDim.x + threadIdx.x; if (e>=E) return;
    int d = ei[E+e];
    int p = atomicAdd(&cursor[d],1);
    eids[p]=e;
}

// ---------- initial node embedding: writes h (f32 channel-major) + hA (bf16 blade-major) ----------
__global__ void embed_kernel(const float* __restrict__ atom_w, const int* __restrict__ zidx,
                             const float* __restrict__ inwT, const float* __restrict__ inb,
                             const float* __restrict__ pos, const float* __restrict__ pmean,
                             const int* __restrict__ batch, float* __restrict__ h,
                             unsigned short* __restrict__ hA, int N){
    int n = blockIdx.x; int o = threadIdx.x;     // 64 threads
    __shared__ float emb[HID];
    emb[o] = atom_w[zidx[n]*HID + o];
    __syncthreads();
    float acc = inb[o];
    for (int i=0;i<HID;i++) acc += emb[i]*inwT[i*HID+o];
    int g = batch[n];
    float px = pos[n*3+0]-pmean[g*3+0];
    float py = pos[n*3+1]-pmean[g*3+1];
    float pz = pos[n*3+2]-pmean[g*3+2];
    float wv = inwT[HID*HID + o];
    float4* hp = (float4*)&h[(size_t)n*CB + o*8];
    hp[0] = make_float4(acc, wv*px, wv*py, wv*pz);
    hp[1] = make_float4(0.f,0.f,0.f,0.f);
    float vals[8] = {acc, wv*px, wv*py, wv*pz, 0.f,0.f,0.f,0.f};
    #pragma unroll
    for (int b=0;b<8;b++) hA[((size_t)b*N + n)*HID + o] = f2bf(vals[b]);
}

// ---------- MFMA MVLinear: z[n][o*8+b] = sum_i hA[b][n][i] * W[g(b)][o][i] ----------
// block: 256 thr = 4 waves; wave = one M-tile of 16 nodes; W bf16 staged in LDS (stride 72).
__global__ __launch_bounds__(256) void proj_kernel(const unsigned short* __restrict__ hA,
                            const unsigned short* __restrict__ WTl, const float* __restrict__ pbl,
                            unsigned short* __restrict__ z16, int N, int Mtiles){
    __shared__ unsigned short wlds[4*64*72];     // [g][o][72] padded rows, 36 KB
    // stage: 256 rows of 64 bf16 each
    {
        int r = threadIdx.x;                     // row = g*64+o
        const int4* src = (const int4*)(WTl + r*64);
        int4* dst = (int4*)(wlds + r*72);
        #pragma unroll
        for (int q=0;q<8;q++) dst[q] = src[q];
    }
    __syncthreads();
    int wv = threadIdx.x>>6, lane = threadIdx.x&63;
    int mt = blockIdx.x*4 + wv;
    if (mt >= Mtiles) return;
    int n0 = mt*16;
    int m = lane&15, quad = lane>>4;
    int nm = min(n0+m, N-1);
    int col = lane&15;
    #pragma unroll
    for (int bp=0; bp<4; bp++){
        int b0 = 2*bp, b1 = b0+1;
        int g0 = gradeOf(b0), g1 = gradeOf(b1);
        // A-frags: 16B per lane, ks 0/1
        const short8 a00 = *(const short8*)(hA + ((size_t)b0*N + nm)*HID + quad*8);
        const short8 a01 = *(const short8*)(hA + ((size_t)b0*N + nm)*HID + 32 + quad*8);
        const short8 a10 = *(const short8*)(hA + ((size_t)b1*N + nm)*HID + quad*8);
        const short8 a11 = *(const short8*)(hA + ((size_t)b1*N + nm)*HID + 32 + quad*8);
        #pragma unroll
        for (int nt=0; nt<4; nt++){
            int o = nt*16 + col;
            const short8 w00 = *(const short8*)(wlds + (g0*64 + o)*72 + quad*8);
            const short8 w01 = *(const short8*)(wlds + (g0*64 + o)*72 + 32 + quad*8);
            const short8 w10 = *(const short8*)(wlds + (g1*64 + o)*72 + quad*8);
            const short8 w11 = *(const short8*)(wlds + (g1*64 + o)*72 + 32 + quad*8);
            floatx4 c0 = {0.f,0.f,0.f,0.f}, c1 = {0.f,0.f,0.f,0.f};
            c0 = __builtin_amdgcn_mfma_f32_16x16x32_bf16(a00, w00, c0, 0,0,0);
            c0 = __builtin_amdgcn_mfma_f32_16x16x32_bf16(a01, w01, c0, 0,0,0);
            c1 = __builtin_amdgcn_mfma_f32_16x16x32_bf16(a10, w10, c1, 0,0,0);
            c1 = __builtin_amdgcn_mfma_f32_16x16x32_bf16(a11, w11, c1, 0,0,0);
            float bias0 = (b0==0) ? pbl[o] : 0.0f;
            #pragma unroll
            for (int r=0;r<4;r++){
                int nn = n0 + quad*4 + r;
                if (nn < N){
                    unsigned p = (unsigned)f2bf(c0[r]+bias0) | ((unsigned)f2bf(c1[r])<<16);
                    *(unsigned*)(z16 + (size_t)nn*CB + o*8 + b0) = p;
                }
            }
        }
    }
}

// ---------- s-logits: one wave per node, bf16 z row ----------
__global__ __launch_bounds__(256) void s_kernel(const unsigned short* __restrict__ z16,
                         const float* __restrict__ a_src_l, const float* __restrict__ a_dst_l,
                         const float* __restrict__ w_src_l, const float* __restrict__ w_dst_l,
                         float* s_src, float* s_dst, int N){
    int n = blockIdx.x*4 + (threadIdx.x>>6);
    int lane = threadIdx.x & 63;
    if (n >= N) return;
    int head = lane>>4;
    const int4 zv0 = *((const int4*)(z16 + (size_t)n*CB) + lane*2);
    const int4 zv1 = *((const int4*)(z16 + (size_t)n*CB) + lane*2 + 1);
    float zz[8] = {bflo(zv0.x),bfhi(zv0.x),bflo(zv0.y),bfhi(zv0.y),
                   bflo(zv0.z),bfhi(zv0.z),bflo(zv0.w),bfhi(zv0.w)};
    float zz2[8] = {bflo(zv1.x),bfhi(zv1.x),bflo(zv1.y),bfhi(zv1.y),
                    bflo(zv1.z),bfhi(zv1.z),bflo(zv1.w),bfhi(zv1.w)};
    // lane covers channel o=lane: elements o*8..o*8+7 -> zv0/zv1 are 16 bf16? No: 16B=8 bf16 each.
    // int4 index lane*2 covers elems 16*lane.. : that's channels 2*lane,2*lane+1. Handle both.
    float ps=0.f, pd=0.f;
    #pragma unroll
    for (int cc=0; cc<2; cc++){
        int o = lane*2 + cc;
        int hh = o>>4;
        const float* zp = cc ? zz2 : zz;
        #pragma unroll
        for (int k=0;k<8;k++){
            int g = gradeOf(k);
            float as = a_src_l[o*8+k]*w_src_l[hh*4+g];
            float ad = a_dst_l[o*8+k]*w_dst_l[hh*4+g];
            ps += zp[k]*as; pd += zp[k]*ad;
        }
    }
    // lane covers channels 2l,2l+1 -> both in head (2l)>>4 = lane>>3. Reduce within 8-lane groups.
    #pragma unroll
    for (int off=1; off<8; off<<=1){
        ps += __shfl_xor(ps, off, 64);
        pd += __shfl_xor(pd, off, 64);
    }
    if ((lane&7)==0){
        int hh = lane>>3;   // head = (lane*2)>>4
        s_src[n*4+hh]=ps; s_dst[n*4+hh]=pd;
    }
}

// ---------- wave-per-node: online-softmax attention + mvSiLU + residual + mvLayerNorm ----------
__global__ __launch_bounds__(256) void agg_kernel(const unsigned short* __restrict__ z16,
                           const float* __restrict__ s_src, const float* __restrict__ s_dst,
                           const float* __restrict__ esc,
                           const int* __restrict__ eids, const int* __restrict__ indptr,
                           const int* __restrict__ ei, int E,
                           const float* __restrict__ silu_a_l, const float* __restrict__ silu_b_l,
                           const float* __restrict__ ln_a_l, float* __restrict__ h,
                           unsigned short* __restrict__ hA, int N){
    __shared__ float lwbuf[4][256];
    int wv = threadIdx.x>>6, lane = threadIdx.x&63;
    float* lwv = lwbuf[wv];
    int n = blockIdx.x*4 + wv;
    if (n >= N) return;
    int beg = indptr[n], end = indptr[n+1];
    float4 sdl = *(const float4*)&s_dst[n*4];
    int h_id = lane>>4;
    float m0=-1e30f,m1=-1e30f,m2=-1e30f,m3=-1e30f;
    float acc[8]; 
    #pragma unroll
    for (int k=0;k<8;k++) acc[k]=0.f;
    float dn = 0.f;
    for (int c0=beg; c0<end; c0+=64){
        int cnt = min(64, end-c0);
        int s = 0;
        float l0=-1e30f,l1=-1e30f,l2=-1e30f,l3=-1e30f;
        if (lane < cnt){
            int e = eids[c0+lane]; s = ei[e];
            float4 sv = *(const float4*)&s_src[s*4];
            float4 ev = *(const float4*)&esc[(size_t)e*4];
            l0 = sv.x+sdl.x+ev.x; l0=(l0>=0.f)?l0:0.2f*l0;
            l1 = sv.y+sdl.y+ev.y; l1=(l1>=0.f)?l1:0.2f*l1;
            l2 = sv.z+sdl.z+ev.z; l2=(l2>=0.f)?l2:0.2f*l2;
            l3 = sv.w+sdl.w+ev.w; l3=(l3>=0.f)?l3:0.2f*l3;
        }
        // chunk max across wave
        float c0m=l0,c1m=l1,c2m=l2,c3m=l3;
        #pragma unroll
        for (int off=1; off<64; off<<=1){
            c0m=fmaxf(c0m,__shfl_xor(c0m,off,64));
            c1m=fmaxf(c1m,__shfl_xor(c1m,off,64));
            c2m=fmaxf(c2m,__shfl_xor(c2m,off,64));
            c3m=fmaxf(c3m,__shfl_xor(c3m,off,64));
        }
        float nm0=fmaxf(m0,c0m), nm1=fmaxf(m1,c1m), nm2=fmaxf(m2,c2m), nm3=fmaxf(m3,c3m);
        // rescale by lane's head
        float mo  = (h_id==0)?m0:((h_id==1)?m1:((h_id==2)?m2:m3));
        float nmo = (h_id==0)?nm0:((h_id==1)?nm1:((h_id==2)?nm2:nm3));
        float sc = __expf(mo-nmo);
        #pragma unroll
        for (int k=0;k<8;k++) acc[k]*=sc;
        dn *= sc;
        m0=nm0; m1=nm1; m2=nm2; m3=nm3;
        // per-lane exp'd weights -> LDS strip
        float4 wquad = make_float4(__expf(l0-nm0),__expf(l1-nm1),__expf(l2-nm2),__expf(l3-nm3));
        *(float4*)&lwv[lane*4] = wquad;
        for (int j=0;j<cnt;j++){
            int sj = __shfl(s, j);
            float wj = lwv[j*4 + h_id];
            const int4 zv = *((const int4*)(z16 + (size_t)sj*CB) + lane);
            acc[0] += wj*bflo(zv.x); acc[1] += wj*bfhi(zv.x);
            acc[2] += wj*bflo(zv.y); acc[3] += wj*bfhi(zv.y);
            acc[4] += wj*bflo(zv.z); acc[5] += wj*bfhi(zv.z);
            acc[6] += wj*bflo(zv.w); acc[7] += wj*bfhi(zv.w);
            dn += wj;
        }
    }
    float inv = 1.0f/(dn + 1e-16f);
    float x[8];
    #pragma unroll
    for (int k=0;k<8;k++) x[k] = acc[k]*inv;
    // mvSiLU (channel c = lane)
    float4 sa = *(const float4*)&silu_a_l[lane*4];
    float4 sb = *(const float4*)&silu_b_l[lane*4];
    float n1 = x[1]*x[1]+x[2]*x[2]+x[3]*x[3];
    float n2 = x[4]*x[4]+x[5]*x[5]+x[6]*x[6];
    float n3 = x[7]*x[7];
    float g0 = 1.0f/(1.0f+__expf(-(sa.x*x[0]+sb.x)));
    float g1 = 1.0f/(1.0f+__expf(-(sa.y*n1+sb.y)));
    float g2 = 1.0f/(1.0f+__expf(-(sa.z*n2+sb.z)));
    float g3 = 1.0f/(1.0f+__expf(-(sa.w*n3+sb.w)));
    float4 r0 = *(const float4*)&h[(size_t)n*CB + lane*8];
    float4 r1 = *(const float4*)&h[(size_t)n*CB + lane*8 + 4];
    float val[8];
    val[0]=g0*x[0]+r0.x; val[1]=g1*x[1]+r0.y; val[2]=g1*x[2]+r0.z; val[3]=g1*x[3]+r0.w;
    val[4]=g2*x[4]+r1.x; val[5]=g2*x[5]+r1.y; val[6]=g2*x[6]+r1.z; val[7]=g3*x[7]+r1.w;
    // mvLayerNorm
    float ss=0.f;
    #pragma unroll
    for (int k=0;k<8;k++) ss += val[k]*val[k];
    float nr = sqrtf(ss);
    #pragma unroll
    for (int off=1; off<64; off<<=1) nr += __shfl_xor(nr, off, 64);
    float mean = nr*(1.0f/64.0f) + 1e-6f;
    float scale = ln_a_l[lane]/mean;
    float out[8];
    #pragma unroll
    for (int k=0;k<8;k++) out[k] = scale*val[k];
    *(float4*)&h[(size_t)n*CB + lane*8]     = make_float4(out[0],out[1],out[2],out[3]);
    *(float4*)&h[(size_t)n*CB + lane*8 + 4] = make_float4(out[4],out[5],out[6],out[7]);
    #pragma unroll
    for (int b=0;b<8;b++) hA[((size_t)b*N + n)*HID + lane] = f2bf(out[b]);
}

// ---------- prepool (scalar blade) + graph readout sum ----------
__global__ void prepool_kernel(const float* __restrict__ h, const float* __restrict__ ppw0T,
                               const float* __restrict__ ppb, const int* __restrict__ batch,
                               float* g, int N){
    int n = blockIdx.x; int o = threadIdx.x;  // 64 threads
    __shared__ float xs[HID];
    xs[o] = h[(size_t)n*CB + o*8];
    __syncthreads();
    float acc = ppb[o];
    for (int i=0;i<HID;i++) acc += xs[i]*ppw0T[i*HID+o];
    atomicAdd(&g[batch[n]*HID + o], acc);
}

__global__ void final_kernel(const float* __restrict__ g, const float* __restrict__ w1T,
                             const float* __restrict__ b1, const float* __restrict__ w2,
                             const float* __restrict__ b2, float* out){
    int gid = blockIdx.x; int o = threadIdx.x;  // 64 threads = 1 wave
    __shared__ float gl[HID];
    gl[o] = g[gid*HID + o]; __syncthreads();
    float a = b1[o];
    for (int i=0;i<HID;i++) a += gl[i]*w1T[i*HID+o];
    float act = a/(1.0f+__expf(-a));
    float p = act * w2[o];
    #pragma unroll
    for (int off=1; off<64; off<<=1) p += __shfl_xor(p,off,64);
    if (o==0) out[gid] = p + b2[0];
}

extern "C" void kernel_launch(void* const* d_in, const int* in_sizes, int n_in,
                              void* d_out, int out_size, void* d_ws, size_t ws_size,
                              hipStream_t stream) {
    const float* pos      = (const float*)d_in[0];
    const int*   zidx     = (const int*)  d_in[1];
    const int*   ei       = (const int*)  d_in[2];
    const int*   batch    = (const int*)  d_in[3];
    const float* atom_w   = (const float*)d_in[4];
    const float* inproj_w = (const float*)d_in[5];
    const float* inproj_b = (const float*)d_in[6];
    const float* edge_w1  = (const float*)d_in[7];
    const float* edge_b1  = (const float*)d_in[8];
    const float* edge_w2  = (const float*)d_in[9];
    const float* edge_b2  = (const float*)d_in[10];
    const float* proj_w   = (const float*)d_in[11];
    const float* proj_b   = (const float*)d_in[12];
    const float* a_src    = (const float*)d_in[13];
    const float* a_dst    = (const float*)d_in[14];
    const float* w_src    = (const float*)d_in[15];
    const float* w_dst    = (const float*)d_in[16];
    const float* ln_a     = (const float*)d_in[17];
    const float* silu_a   = (const float*)d_in[18];
    const float* silu_b   = (const float*)d_in[19];
    const float* prepool_w= (const float*)d_in[20];
    const float* prepool_b= (const float*)d_in[21];
    const float* post_w1  = (const float*)d_in[22];
    const float* post_b1  = (const float*)d_in[23];
    const float* post_w2  = (const float*)d_in[24];
    const float* post_b2  = (const float*)d_in[25];
    float* out = (float*)d_out;

    const int N = in_sizes[0]/3;
    const int E = in_sizes[2]/2;
    const int Mtiles = (N+15)/16;

    float* wsf = (float*)d_ws;
    size_t off = 0;
    auto alloc = [&](size_t nelem){ size_t r = off; off += (nelem + 63) & ~(size_t)63; return r; };
    size_t o_counts = alloc(N);          // int
    size_t o_possum = alloc(NG*3);
    size_t o_pcnt   = alloc(NG);
    size_t o_g      = alloc(NG*HID);
    size_t zero_end = off;
    size_t o_indptr = alloc(N+1);        // int
    size_t o_cursor = alloc(N);          // int
    size_t o_eids   = alloc(E);          // int
    size_t o_pmean  = alloc(NG*3);
    size_t o_esc    = alloc((size_t)E*4);
    size_t o_ssrc   = alloc((size_t)N*4);
    size_t o_sdst   = alloc((size_t)N*4);
    size_t o_inwT   = alloc(65*HID);
    size_t o_WTbf   = alloc((size_t)LAYERS*4*64*64/2);   // ushort
    size_t o_ppw0T  = alloc(HID*HID);
    size_t o_w1T    = alloc(HID*HID);
    size_t o_h      = alloc((size_t)N*CB);
    size_t o_z16    = alloc((size_t)N*CB/2);             // ushort
    size_t o_hA     = alloc((size_t)N*CB/2);             // ushort

    int*   counts = (int*)(wsf + o_counts);
    float* possum = wsf + o_possum;
    float* pcnt   = wsf + o_pcnt;
    float* gbuf   = wsf + o_g;
    int*   indptr = (int*)(wsf + o_indptr);
    int*   cursor = (int*)(wsf + o_cursor);
    int*   eids   = (int*)(wsf + o_eids);
    float* pmean  = wsf + o_pmean;
    float* esc    = wsf + o_esc;
    float* ssrc   = wsf + o_ssrc;
    float* sdst   = wsf + o_sdst;
    float* inwT   = wsf + o_inwT;
    unsigned short* WTbf = (unsigned short*)(wsf + o_WTbf);
    float* ppw0T  = wsf + o_ppw0T;
    float* w1T    = wsf + o_w1T;
    float* hbuf   = wsf + o_h;
    unsigned short* z16 = (unsigned short*)(wsf + o_z16);
    unsigned short* hA  = (unsigned short*)(wsf + o_hA);

    hipMemsetAsync(wsf, 0, zero_end*sizeof(float), stream);

    {
        int total = LAYERS*4*64*64 + 65*HID + 2*HID*HID;
        prep_kernel<<<(total+255)/256, 256, 0, stream>>>(proj_w, inproj_w, prepool_w, post_w1,
                                                         WTbf, inwT, ppw0T, w1T);
    }
    node_stats_kernel<<<(N+255)/256, 256, 0, stream>>>(pos, batch, possum, pcnt, N);
    edge_kernel<<<(E+255)/256, 256, 0, stream>>>(pos, ei, E, edge_w1, edge_b1, edge_w2, edge_b2,
                                                 esc, counts);
    scan_kernel<<<1, 1024, 0, stream>>>(counts, indptr, cursor, N, possum, pcnt, pmean);
    fill_kernel<<<(E+255)/256, 256, 0, stream>>>(ei, E, cursor, eids);
    embed_kernel<<<N, HID, 0, stream>>>(atom_w, zidx, inwT, inproj_b, pos, pmean, batch,
                                        hbuf, hA, N);

    for (int l=0; l<LAYERS; l++){
        proj_kernel<<<(Mtiles+3)/4, 256, 0, stream>>>(hA, WTbf + (size_t)l*4*64*64,
                                                      proj_b + l*HID, z16, N, Mtiles);
        s_kernel<<<(N+3)/4, 256, 0, stream>>>(z16, a_src + l*512, a_dst + l*512,
                                              w_src + l*16, w_dst + l*16, ssrc, sdst, N);
        agg_kernel<<<(N+3)/4, 256, 0, stream>>>(z16, ssrc, sdst, esc, eids, indptr, ei, E,
                                                silu_a + l*HID*4, silu_b + l*HID*4,
                                                ln_a + l*HID, hbuf, hA, N);
    }

    prepool_kernel<<<N, HID, 0, stream>>>(hbuf, ppw0T, prepool_b, batch, gbuf, N);
    final_kernel<<<NG, HID, 0, stream>>>(gbuf, w1T, post_b1, post_w2, post_b2, out);
}

// Round 4
// 643.176 us; speedup vs baseline: 1.7516x; 1.0565x over previous
//
#include <hip/hip_runtime.h>
#include <hip/hip_bf16.h>
#include <math.h>

#define HID 64
#define HEADS 4
#define LAYERS 4
#define NRBF 20
#define NG 256
#define CB 512     // HID*8 floats per node (channels x blades)

typedef __attribute__((ext_vector_type(8))) short short8;
typedef __attribute__((ext_vector_type(4))) float floatx4;

__device__ __forceinline__ int gradeOf(int b){ return (b==0)?0:((b<4)?1:((b<7)?2:3)); }
__device__ __forceinline__ unsigned short f2bf(float f){
    __hip_bfloat16 h = __float2bfloat16(f);
    return *(unsigned short*)&h;
}
__device__ __forceinline__ float bflo(int u){ return __uint_as_float(((unsigned)u)<<16); }
__device__ __forceinline__ float bfhi(int u){ return __uint_as_float(((unsigned)u)&0xFFFF0000u); }

// ---------- prep: WTbf = bf16(proj_w); f32 transposes; per-head s-bias scalars ----------
__global__ void prep_kernel(const float* __restrict__ proj_w, const float* __restrict__ inproj_w,
                            const float* __restrict__ prepool_w, const float* __restrict__ post_w1,
                            const float* __restrict__ a_src, const float* __restrict__ a_dst,
                            const float* __restrict__ w_src, const float* __restrict__ w_dst,
                            const float* __restrict__ proj_b,
                            unsigned short* __restrict__ WTbf, float* __restrict__ inwT,
                            float* __restrict__ ppw0T, float* __restrict__ w1T,
                            float* __restrict__ sbf){
    int idx = blockIdx.x*256 + threadIdx.x;
    const int szW = LAYERS*4*64*64;          // 65536
    const int e1 = szW + 65*HID;
    const int e2 = e1 + HID*HID;
    const int e3 = e2 + HID*HID;
    if (idx < szW){
        WTbf[idx] = f2bf(proj_w[idx]);
    } else if (idx < e1){
        int r = idx - szW; int i = r/HID, o = r%HID;
        inwT[r] = inproj_w[o*65 + i];
    } else if (idx < e2){
        int r = idx - e1; int i = r/HID, o = r%HID;
        ppw0T[r] = prepool_w[o*HID + i];
    } else if (idx < e3){
        int r = idx - e2; int i = r/HID, o = r%HID;
        w1T[r] = post_w1[o*HID + i];
    } else if (idx < e3 + 2*LAYERS*HEADS){
        int r = idx - e3;                    // r = (l*2+type)*4+h
        int h = r & 3; int type = (r>>2)&1; int l = r>>3;
        const float* a = type ? a_dst : a_src;
        const float* w = type ? w_dst : w_src;
        float wh = w[l*16 + h*4 + 0];        // grade 0
        float s = 0.f;
        for (int c=0;c<16;c++)
            s += a[l*512 + (h*16+c)*8 + 0] * wh * proj_b[l*64 + h*16 + c];
        sbf[r] = s;
    }
}

// ---------- per-graph position sums for centering ----------
__global__ void node_stats_kernel(const float* __restrict__ pos, const int* __restrict__ batch,
                                  float* possum, float* pcnt, int N){
    int n = blockIdx.x*256 + threadIdx.x; if (n>=N) return;
    int g = batch[n];
    atomicAdd(&possum[g*3+0], pos[n*3+0]);
    atomicAdd(&possum[g*3+1], pos[n*3+1]);
    atomicAdd(&possum[g*3+2], pos[n*3+2]);
    atomicAdd(&pcnt[g], 1.0f);
}

// ---------- edge MLP: dist -> RBF(20) -> 64 (silu) -> 4, plus dst-degree count ----------
__global__ void edge_kernel(const float* __restrict__ pos, const int* __restrict__ ei, int E,
                            const float* __restrict__ ew1, const float* __restrict__ eb1,
                            const float* __restrict__ ew2, const float* __restrict__ eb2,
                            float* __restrict__ edge_scalar, int* counts){
    __shared__ float w1[HID*NRBF], b1[HID], w2[HEADS*HID], b2s[HEADS];
    for (int i=threadIdx.x;i<HID*NRBF;i+=blockDim.x) w1[i]=ew1[i];
    for (int i=threadIdx.x;i<HID;i+=blockDim.x) b1[i]=eb1[i];
    for (int i=threadIdx.x;i<HEADS*HID;i+=blockDim.x) w2[i]=ew2[i];
    if (threadIdx.x<HEADS) b2s[threadIdx.x]=eb2[threadIdx.x];
    __syncthreads();
    int e = blockIdx.x*blockDim.x + threadIdx.x; if (e>=E) return;
    int s = ei[e], d = ei[E+e];
    float dx = pos[s*3+0]-pos[d*3+0];
    float dy = pos[s*3+1]-pos[d*3+1];
    float dz = pos[s*3+2]-pos[d*3+2];
    float dist = sqrtf(dx*dx+dy*dy+dz*dz);
    float t0 = dist * (19.0f/10.0f);
    float rbf[NRBF];
    #pragma unroll
    for (int k=0;k<NRBF;k++){ float a = t0 - (float)k; rbf[k]=__expf(-0.5f*a*a); }
    float acc0=b2s[0], acc1=b2s[1], acc2=b2s[2], acc3=b2s[3];
    for (int o=0;o<HID;o++){
        float hv = b1[o];
        #pragma unroll
        for (int k=0;k<NRBF;k++) hv += rbf[k]*w1[o*NRBF+k];
        float act = hv * (1.0f/(1.0f+__expf(-hv)));
        acc0 += act*w2[0*HID+o]; acc1 += act*w2[1*HID+o];
        acc2 += act*w2[2*HID+o]; acc3 += act*w2[3*HID+o];
    }
    float4* ep = (float4*)&edge_scalar[e*4];
    ep[0] = make_float4(acc0,acc1,acc2,acc3);
    atomicAdd(&counts[d],1);
}

// ---------- single-block shuffle scan -> CSR indptr + cursor; pos means ----------
__global__ void scan_kernel(const int* __restrict__ counts, int* indptr, int* cursor, int N,
                            const float* __restrict__ possum, const float* __restrict__ pcnt,
                            float* pmean){
    __shared__ int wsum[16];
    __shared__ int carry_s;
    int t = threadIdx.x; int lane = t&63, w = t>>6;
    if (t==0) carry_s = 0;
    __syncthreads();
    for (int base=0; base<N; base+=1024){
        int v = (base+t<N)? counts[base+t] : 0;
        int x = v;
        #pragma unroll
        for (int off=1; off<64; off<<=1){ int y=__shfl_up(x,off,64); if (lane>=off) x+=y; }
        if (lane==63) wsum[w]=x;
        __syncthreads();
        if (w==0 && lane<16){
            int s = wsum[lane];
            #pragma unroll
            for (int off=1; off<16; off<<=1){ int y=__shfl_up(s,off,64); if (lane>=off) s+=y; }
            wsum[lane]=s;
        }
        __syncthreads();
        int excl = carry_s + (w>0? wsum[w-1]:0) + x - v;
        if (base+t<N){ indptr[base+t]=excl; cursor[base+t]=excl; }
        __syncthreads();
        if (t==1023) carry_s = carry_s + wsum[15];
        __syncthreads();
    }
    if (t==0) indptr[N]=carry_s;
    for (int i=t;i<NG;i+=1024){
        float c = pcnt[i]; float cm = c>1.0f?c:1.0f;
        pmean[i*3+0]=possum[i*3+0]/cm;
        pmean[i*3+1]=possum[i*3+1]/cm;
        pmean[i*3+2]=possum[i*3+2]/cm;
    }
}

__global__ void fill_kernel(const int* __restrict__ ei, int E, int* cursor, int* eids){
    int e = blockIdx.x*blockDim.x + threadIdx.x; if (e>=E) return;
    int d = ei[E+e];
    int p = atomicAdd(&cursor[d],1);
    eids[p]=e;
}

// ---------- initial node embedding: writes h (f32 channel-major) + hA (bf16 blade-major) ----------
__global__ void embed_kernel(const float* __restrict__ atom_w, const int* __restrict__ zidx,
                             const float* __restrict__ inwT, const float* __restrict__ inb,
                             const float* __restrict__ pos, const float* __restrict__ pmean,
                             const int* __restrict__ batch, float* __restrict__ h,
                             unsigned short* __restrict__ hA, int N){
    int n = blockIdx.x; int o = threadIdx.x;     // 64 threads
    __shared__ float emb[HID];
    emb[o] = atom_w[zidx[n]*HID + o];
    __syncthreads();
    float acc = inb[o];
    for (int i=0;i<HID;i++) acc += emb[i]*inwT[i*HID+o];
    int g = batch[n];
    float px = pos[n*3+0]-pmean[g*3+0];
    float py = pos[n*3+1]-pmean[g*3+1];
    float pz = pos[n*3+2]-pmean[g*3+2];
    float wv = inwT[HID*HID + o];
    float4* hp = (float4*)&h[(size_t)n*CB + o*8];
    hp[0] = make_float4(acc, wv*px, wv*py, wv*pz);
    hp[1] = make_float4(0.f,0.f,0.f,0.f);
    float vals[8] = {acc, wv*px, wv*py, wv*pz, 0.f,0.f,0.f,0.f};
    #pragma unroll
    for (int b=0;b<8;b++) hA[((size_t)b*N + n)*HID + o] = f2bf(vals[b]);
}

// ---------- MFMA MVLinear + fused s-logits; one wave per 16-node M-tile, W from L1/L2 ----------
__global__ __launch_bounds__(64) void proj_kernel(const unsigned short* __restrict__ hA,
                            const unsigned short* __restrict__ WTl, const float* __restrict__ pbl,
                            const float* __restrict__ a_src_l, const float* __restrict__ a_dst_l,
                            const float* __restrict__ w_src_l, const float* __restrict__ w_dst_l,
                            const float* __restrict__ sb_l,
                            unsigned short* __restrict__ z16, float* __restrict__ s_src,
                            float* __restrict__ s_dst, int N){
    int lane = threadIdx.x;
    int n0 = blockIdx.x*16;
    int m = lane&15, quad = lane>>4;
    int nm = min(n0+m, N-1);
    int col = m;
    float pss[4][4], psd[4][4];
    #pragma unroll
    for (int a=0;a<4;a++)
        #pragma unroll
        for (int r=0;r<4;r++){ pss[a][r]=0.f; psd[a][r]=0.f; }
    #pragma unroll
    for (int bp=0; bp<4; bp++){
        const int b0 = 2*bp, b1 = b0+1;
        const int g0 = gradeOf(b0), g1 = gradeOf(b1);
        const short8 a00 = *(const short8*)(hA + ((size_t)b0*N + nm)*HID + quad*8);
        const short8 a01 = *(const short8*)(hA + ((size_t)b0*N + nm)*HID + 32 + quad*8);
        const short8 a10 = *(const short8*)(hA + ((size_t)b1*N + nm)*HID + quad*8);
        const short8 a11 = *(const short8*)(hA + ((size_t)b1*N + nm)*HID + 32 + quad*8);
        #pragma unroll
        for (int nt=0; nt<4; nt++){
            int o = nt*16 + col;
            const short8 w00 = *(const short8*)(WTl + (g0*64 + o)*64 + quad*8);
            const short8 w01 = *(const short8*)(WTl + (g0*64 + o)*64 + 32 + quad*8);
            short8 w10, w11;
            if (g1==g0){ w10 = w00; w11 = w01; }
            else {
                w10 = *(const short8*)(WTl + (g1*64 + o)*64 + quad*8);
                w11 = *(const short8*)(WTl + (g1*64 + o)*64 + 32 + quad*8);
            }
            floatx4 c0 = {0.f,0.f,0.f,0.f}, c1 = {0.f,0.f,0.f,0.f};
            c0 = __builtin_amdgcn_mfma_f32_16x16x32_bf16(a00, w00, c0, 0,0,0);
            c0 = __builtin_amdgcn_mfma_f32_16x16x32_bf16(a01, w01, c0, 0,0,0);
            c1 = __builtin_amdgcn_mfma_f32_16x16x32_bf16(a10, w10, c1, 0,0,0);
            c1 = __builtin_amdgcn_mfma_f32_16x16x32_bf16(a11, w11, c1, 0,0,0);
            // fold attention contraction for this lane's o, blades b0/b1
            float as0 = a_src_l[o*8+b0]*w_src_l[nt*4+g0];
            float as1 = a_src_l[o*8+b1]*w_src_l[nt*4+g1];
            float ad0 = a_dst_l[o*8+b0]*w_dst_l[nt*4+g0];
            float ad1 = a_dst_l[o*8+b1]*w_dst_l[nt*4+g1];
            float bias0 = (bp==0) ? pbl[o] : 0.0f;
            #pragma unroll
            for (int r=0;r<4;r++){
                float v0 = c0[r], v1 = c1[r];
                pss[nt][r] += v0*as0 + v1*as1;
                psd[nt][r] += v0*ad0 + v1*ad1;
                int nn = n0 + quad*4 + r;
                if (nn < N){
                    unsigned p = (unsigned)f2bf(v0+bias0) | ((unsigned)f2bf(v1)<<16);
                    *(unsigned*)(z16 + (size_t)nn*CB + o*8 + b0) = p;
                }
            }
        }
    }
    // reduce s-partials across the 16 col-lanes of each quad; head = nt
    #pragma unroll
    for (int nt=0; nt<4; nt++){
        #pragma unroll
        for (int r=0;r<4;r++){
            float vs = pss[nt][r], vd = psd[nt][r];
            #pragma unroll
            for (int off=1; off<16; off<<=1){
                vs += __shfl_xor(vs, off, 64);
                vd += __shfl_xor(vd, off, 64);
            }
            int nn = n0 + quad*4 + r;
            if (col==0 && nn<N){
                s_src[nn*4+nt] = vs + sb_l[nt];
                s_dst[nn*4+nt] = vd + sb_l[4+nt];
            }
        }
    }
}

// ---------- wave-per-node: online-softmax attention + mvSiLU + residual + mvLayerNorm ----------
__global__ __launch_bounds__(256) void agg_kernel(const unsigned short* __restrict__ z16,
                           const float* __restrict__ s_src, const float* __restrict__ s_dst,
                           const float* __restrict__ esc,
                           const int* __restrict__ eids, const int* __restrict__ indptr,
                           const int* __restrict__ ei, int E,
                           const float* __restrict__ silu_a_l, const float* __restrict__ silu_b_l,
                           const float* __restrict__ ln_a_l, float* __restrict__ h,
                           unsigned short* __restrict__ hA, int N){
    __shared__ float lwbuf[4][256];
    int wv = threadIdx.x>>6, lane = threadIdx.x&63;
    float* lwv = lwbuf[wv];
    int n = blockIdx.x*4 + wv;
    if (n >= N) return;
    int beg = indptr[n], end = indptr[n+1];
    float4 sdl = *(const float4*)&s_dst[n*4];
    int h_id = lane>>4;
    float m0=-1e30f,m1=-1e30f,m2=-1e30f,m3=-1e30f;
    float acc[8];
    #pragma unroll
    for (int k=0;k<8;k++) acc[k]=0.f;
    float dn = 0.f;
    for (int c0=beg; c0<end; c0+=64){
        int cnt = min(64, end-c0);
        int s = 0;
        float l0=-1e30f,l1=-1e30f,l2=-1e30f,l3=-1e30f;
        if (lane < cnt){
            int e = eids[c0+lane]; s = ei[e];
            float4 sv = *(const float4*)&s_src[s*4];
            float4 ev = *(const float4*)&esc[(size_t)e*4];
            l0 = sv.x+sdl.x+ev.x; l0=(l0>=0.f)?l0:0.2f*l0;
            l1 = sv.y+sdl.y+ev.y; l1=(l1>=0.f)?l1:0.2f*l1;
            l2 = sv.z+sdl.z+ev.z; l2=(l2>=0.f)?l2:0.2f*l2;
            l3 = sv.w+sdl.w+ev.w; l3=(l3>=0.f)?l3:0.2f*l3;
        }
        float c0m=l0,c1m=l1,c2m=l2,c3m=l3;
        #pragma unroll
        for (int off=1; off<64; off<<=1){
            c0m=fmaxf(c0m,__shfl_xor(c0m,off,64));
            c1m=fmaxf(c1m,__shfl_xor(c1m,off,64));
            c2m=fmaxf(c2m,__shfl_xor(c2m,off,64));
            c3m=fmaxf(c3m,__shfl_xor(c3m,off,64));
        }
        float nm0=fmaxf(m0,c0m), nm1=fmaxf(m1,c1m), nm2=fmaxf(m2,c2m), nm3=fmaxf(m3,c3m);
        float mo  = (h_id==0)?m0:((h_id==1)?m1:((h_id==2)?m2:m3));
        float nmo = (h_id==0)?nm0:((h_id==1)?nm1:((h_id==2)?nm2:nm3));
        float sc = __expf(mo-nmo);
        #pragma unroll
        for (int k=0;k<8;k++) acc[k]*=sc;
        dn *= sc;
        m0=nm0; m1=nm1; m2=nm2; m3=nm3;
        // padded lanes (lane>=cnt) produce exp(-1e30-x)=0 -> zero weight, s=0 -> safe address
        float4 wquad = make_float4(__expf(l0-nm0),__expf(l1-nm1),__expf(l2-nm2),__expf(l3-nm3));
        *(float4*)&lwv[lane*4] = wquad;
        int rc = (cnt+3)&~3;
        for (int j=0;j<rc;j+=4){
            int s0 = __shfl(s, j+0), s1 = __shfl(s, j+1);
            int s2 = __shfl(s, j+2), s3 = __shfl(s, j+3);
            const int4 zv0 = *((const int4*)(z16 + (size_t)s0*CB) + lane);
            const int4 zv1 = *((const int4*)(z16 + (size_t)s1*CB) + lane);
            const int4 zv2 = *((const int4*)(z16 + (size_t)s2*CB) + lane);
            const int4 zv3 = *((const int4*)(z16 + (size_t)s3*CB) + lane);
            float w0 = lwv[(j+0)*4 + h_id], w1 = lwv[(j+1)*4 + h_id];
            float w2 = lwv[(j+2)*4 + h_id], w3 = lwv[(j+3)*4 + h_id];
            acc[0] += w0*bflo(zv0.x); acc[1] += w0*bfhi(zv0.x);
            acc[2] += w0*bflo(zv0.y); acc[3] += w0*bfhi(zv0.y);
            acc[4] += w0*bflo(zv0.z); acc[5] += w0*bfhi(zv0.z);
            acc[6] += w0*bflo(zv0.w); acc[7] += w0*bfhi(zv0.w);
            acc[0] += w1*bflo(zv1.x); acc[1] += w1*bfhi(zv1.x);
            acc[2] += w1*bflo(zv1.y); acc[3] += w1*bfhi(zv1.y);
            acc[4] += w1*bflo(zv1.z); acc[5] += w1*bfhi(zv1.z);
            acc[6] += w1*bflo(zv1.w); acc[7] += w1*bfhi(zv1.w);
            acc[0] += w2*bflo(zv2.x); acc[1] += w2*bfhi(zv2.x);
            acc[2] += w2*bflo(zv2.y); acc[3] += w2*bfhi(zv2.y);
            acc[4] += w2*bflo(zv2.z); acc[5] += w2*bfhi(zv2.z);
            acc[6] += w2*bflo(zv2.w); acc[7] += w2*bfhi(zv2.w);
            acc[0] += w3*bflo(zv3.x); acc[1] += w3*bfhi(zv3.x);
            acc[2] += w3*bflo(zv3.y); acc[3] += w3*bfhi(zv3.y);
            acc[4] += w3*bflo(zv3.z); acc[5] += w3*bfhi(zv3.z);
            acc[6] += w3*bflo(zv3.w); acc[7] += w3*bfhi(zv3.w);
            dn += w0+w1+w2+w3;
        }
    }
    float inv = 1.0f/(dn + 1e-16f);
    float x[8];
    #pragma unroll
    for (int k=0;k<8;k++) x[k] = acc[k]*inv;
    float4 sa = *(const float4*)&silu_a_l[lane*4];
    float4 sb = *(const float4*)&silu_b_l[lane*4];
    float n1 = x[1]*x[1]+x[2]*x[2]+x[3]*x[3];
    float n2 = x[4]*x[4]+x[5]*x[5]+x[6]*x[6];
    float n3 = x[7]*x[7];
    float g0 = 1.0f/(1.0f+__expf(-(sa.x*x[0]+sb.x)));
    float g1 = 1.0f/(1.0f+__expf(-(sa.y*n1+sb.y)));
    float g2 = 1.0f/(1.0f+__expf(-(sa.z*n2+sb.z)));
    float g3 = 1.0f/(1.0f+__expf(-(sa.w*n3+sb.w)));
    float4 r0 = *(const float4*)&h[(size_t)n*CB + lane*8];
    float4 r1 = *(const float4*)&h[(size_t)n*CB + lane*8 + 4];
    float val[8];
    val[0]=g0*x[0]+r0.x; val[1]=g1*x[1]+r0.y; val[2]=g1*x[2]+r0.z; val[3]=g1*x[3]+r0.w;
    val[4]=g2*x[4]+r1.x; val[5]=g2*x[5]+r1.y; val[6]=g2*x[6]+r1.z; val[7]=g3*x[7]+r1.w;
    float ss=0.f;
    #pragma unroll
    for (int k=0;k<8;k++) ss += val[k]*val[k];
    float nr = sqrtf(ss);
    #pragma unroll
    for (int off=1; off<64; off<<=1) nr += __shfl_xor(nr, off, 64);
    float mean = nr*(1.0f/64.0f) + 1e-6f;
    float scale = ln_a_l[lane]/mean;
    float outv[8];
    #pragma unroll
    for (int k=0;k<8;k++) outv[k] = scale*val[k];
    *(float4*)&h[(size_t)n*CB + lane*8]     = make_float4(outv[0],outv[1],outv[2],outv[3]);
    *(float4*)&h[(size_t)n*CB + lane*8 + 4] = make_float4(outv[4],outv[5],outv[6],outv[7]);
    #pragma unroll
    for (int b=0;b<8;b++) hA[((size_t)b*N + n)*HID + lane] = f2bf(outv[b]);
}

// ---------- prepool (scalar blade) + graph readout sum ----------
__global__ void prepool_kernel(const float* __restrict__ h, const float* __restrict__ ppw0T,
                               const float* __restrict__ ppb, const int* __restrict__ batch,
                               float* g, int N){
    int n = blockIdx.x; int o = threadIdx.x;  // 64 threads
    __shared__ float xs[HID];
    xs[o] = h[(size_t)n*CB + o*8];
    __syncthreads();
    float acc = ppb[o];
    for (int i=0;i<HID;i++) acc += xs[i]*ppw0T[i*HID+o];
    atomicAdd(&g[batch[n]*HID + o], acc);
}

__global__ void final_kernel(const float* __restrict__ g, const float* __restrict__ w1T,
                             const float* __restrict__ b1, const float* __restrict__ w2,
                             const float* __restrict__ b2, float* out){
    int gid = blockIdx.x; int o = threadIdx.x;  // 64 threads = 1 wave
    __shared__ float gl[HID];
    gl[o] = g[gid*HID + o]; __syncthreads();
    float a = b1[o];
    for (int i=0;i<HID;i++) a += gl[i]*w1T[i*HID+o];
    float act = a/(1.0f+__expf(-a));
    float p = act * w2[o];
    #pragma unroll
    for (int off=1; off<64; off<<=1) p += __shfl_xor(p,off,64);
    if (o==0) out[gid] = p + b2[0];
}

extern "C" void kernel_launch(void* const* d_in, const int* in_sizes, int n_in,
                              void* d_out, int out_size, void* d_ws, size_t ws_size,
                              hipStream_t stream) {
    const float* pos      = (const float*)d_in[0];
    const int*   zidx     = (const int*)  d_in[1];
    const int*   ei       = (const int*)  d_in[2];
    const int*   batch    = (const int*)  d_in[3];
    const float* atom_w   = (const float*)d_in[4];
    const float* inproj_w = (const float*)d_in[5];
    const float* inproj_b = (const float*)d_in[6];
    const float* edge_w1  = (const float*)d_in[7];
    const float* edge_b1  = (const float*)d_in[8];
    const float* edge_w2  = (const float*)d_in[9];
    const float* edge_b2  = (const float*)d_in[10];
    const float* proj_w   = (const float*)d_in[11];
    const float* proj_b   = (const float*)d_in[12];
    const float* a_src    = (const float*)d_in[13];
    const float* a_dst    = (const float*)d_in[14];
    const float* w_src    = (const float*)d_in[15];
    const float* w_dst    = (const float*)d_in[16];
    const float* ln_a     = (const float*)d_in[17];
    const float* silu_a   = (const float*)d_in[18];
    const float* silu_b   = (const float*)d_in[19];
    const float* prepool_w= (const float*)d_in[20];
    const float* prepool_b= (const float*)d_in[21];
    const float* post_w1  = (const float*)d_in[22];
    const float* post_b1  = (const float*)d_in[23];
    const float* post_w2  = (const float*)d_in[24];
    const float* post_b2  = (const float*)d_in[25];
    float* out = (float*)d_out;

    const int N = in_sizes[0]/3;
    const int E = in_sizes[2]/2;
    const int Mtiles = (N+15)/16;

    float* wsf = (float*)d_ws;
    size_t off = 0;
    auto alloc = [&](size_t nelem){ size_t r = off; off += (nelem + 63) & ~(size_t)63; return r; };
    size_t o_counts = alloc(N);          // int
    size_t o_possum = alloc(NG*3);
    size_t o_pcnt   = alloc(NG);
    size_t o_g      = alloc(NG*HID);
    size_t zero_end = off;
    size_t o_indptr = alloc(N+1);        // int
    size_t o_cursor = alloc(N);          // int
    size_t o_eids   = alloc(E);          // int
    size_t o_pmean  = alloc(NG*3);
    size_t o_esc    = alloc((size_t)E*4);
    size_t o_ssrc   = alloc((size_t)N*4);
    size_t o_sdst   = alloc((size_t)N*4);
    size_t o_inwT   = alloc(65*HID);
    size_t o_WTbf   = alloc((size_t)LAYERS*4*64*64/2);   // ushort
    size_t o_ppw0T  = alloc(HID*HID);
    size_t o_w1T    = alloc(HID*HID);
    size_t o_sbf    = alloc(2*LAYERS*HEADS);
    size_t o_h      = alloc((size_t)N*CB);
    size_t o_z16    = alloc((size_t)N*CB/2);             // ushort
    size_t o_hA     = alloc((size_t)N*CB/2);             // ushort

    int*   counts = (int*)(wsf + o_counts);
    float* possum = wsf + o_possum;
    float* pcnt   = wsf + o_pcnt;
    float* gbuf   = wsf + o_g;
    int*   indptr = (int*)(wsf + o_indptr);
    int*   cursor = (int*)(wsf + o_cursor);
    int*   eids   = (int*)(wsf + o_eids);
    float* pmean  = wsf + o_pmean;
    float* esc    = wsf + o_esc;
    float* ssrc   = wsf + o_ssrc;
    float* sdst   = wsf + o_sdst;
    float* inwT   = wsf + o_inwT;
    unsigned short* WTbf = (unsigned short*)(wsf + o_WTbf);
    float* ppw0T  = wsf + o_ppw0T;
    float* w1T    = wsf + o_w1T;
    float* sbf    = wsf + o_sbf;
    float* hbuf   = wsf + o_h;
    unsigned short* z16 = (unsigned short*)(wsf + o_z16);
    unsigned short* hA  = (unsigned short*)(wsf + o_hA);

    hipMemsetAsync(wsf, 0, zero_end*sizeof(float), stream);

    {
        int total = LAYERS*4*64*64 + 65*HID + 2*HID*HID + 2*LAYERS*HEADS;
        prep_kernel<<<(total+255)/256, 256, 0, stream>>>(proj_w, inproj_w, prepool_w, post_w1,
                                                         a_src, a_dst, w_src, w_dst, proj_b,
                                                         WTbf, inwT, ppw0T, w1T, sbf);
    }
    node_stats_kernel<<<(N+255)/256, 256, 0, stream>>>(pos, batch, possum, pcnt, N);
    edge_kernel<<<(E+255)/256, 256, 0, stream>>>(pos, ei, E, edge_w1, edge_b1, edge_w2, edge_b2,
                                                 esc, counts);
    scan_kernel<<<1, 1024, 0, stream>>>(counts, indptr, cursor, N, possum, pcnt, pmean);
    fill_kernel<<<(E+255)/256, 256, 0, stream>>>(ei, E, cursor, eids);
    embed_kernel<<<N, HID, 0, stream>>>(atom_w, zidx, inwT, inproj_b, pos, pmean, batch,
                                        hbuf, hA, N);

    for (int l=0; l<LAYERS; l++){
        proj_kernel<<<Mtiles, 64, 0, stream>>>(hA, WTbf + (size_t)l*4*64*64, proj_b + l*HID,
                                               a_src + l*512, a_dst + l*512,
                                               w_src + l*16, w_dst + l*16, sbf + l*8,
                                               z16, ssrc, sdst, N);
        agg_kernel<<<(N+3)/4, 256, 0, stream>>>(z16, ssrc, sdst, esc, eids, indptr, ei, E,
                                                silu_a + l*HID*4, silu_b + l*HID*4,
                                                ln_a + l*HID, hbuf, hA, N);
    }

    prepool_kernel<<<N, HID, 0, stream>>>(hbuf, ppw0T, prepool_b, batch, gbuf, N);
    final_kernel<<<NG, HID, 0, stream>>>(gbuf, w1T, post_b1, post_w2, post_b2, out);
}